// Round 3
// baseline (2766.664 us; speedup 1.0000x reference)
//
#include <hip/hip_runtime.h>
#include <hip/hip_bf16.h>
#include <math.h>

// NODE_DIM=3, EMBED=16
#define ND 3
#define EM 16
#define BK 9             // log2(nodes per bucket)
#define BN 512           // nodes per bucket
#define ACCP 17          // padded LDS accumulator stride (bank-conflict break)

__device__ __forceinline__ float sp(float x) {
    // jax.nn.softplus = max(x,0) + log1p(exp(-|x|))
    return fmaxf(x, 0.0f) + log1pf(expf(-fabsf(x)));
}

// ---- bucket pipeline -------------------------------------------------------

__global__ __launch_bounds__(1024) void zero_gcur(int* __restrict__ gcur, int NB) {
    int t = threadIdx.x;
    if (t < NB) gcur[t] = 0;
}

// Histogram of dst-buckets into gcur. 4096 edges per WG.
__global__ __launch_bounds__(256) void hist_kernel(
    const int* __restrict__ ei, int* __restrict__ gcur, int E, int NB)
{
    __shared__ int h[1024];
    int t = threadIdx.x;
    for (int i = t; i < NB; i += 256) h[i] = 0;
    __syncthreads();
    int base = blockIdx.x * 4096;
#pragma unroll
    for (int i = 0; i < 16; i++) {
        int e = base + i * 256 + t;
        if (e < E) atomicAdd(&h[ei[(size_t)E + e] >> BK], 1);
    }
    __syncthreads();
    for (int i = t; i < NB; i += 256) if (h[i]) atomicAdd(&gcur[i], h[i]);
}

// Exclusive scan of bucket counts -> bbase[NB+1]; reset gcur for reuse as cursors.
__global__ __launch_bounds__(1024) void scan_kernel(
    int* __restrict__ gcur, int* __restrict__ bbase, int NB, int E)
{
    __shared__ int sd[1024];
    int t = threadIdx.x;
    int v = (t < NB) ? gcur[t] : 0;
    sd[t] = v;
    __syncthreads();
    for (int off = 1; off < 1024; off <<= 1) {
        int a = (t >= off) ? sd[t - off] : 0;
        __syncthreads();
        sd[t] += a;
        __syncthreads();
    }
    if (t < NB) { bbase[t] = sd[t] - v; gcur[t] = 0; }
    if (t == 0) bbase[NB] = E;
}

// Multisplit: stage 4096 edges in regs, LDS histogram, one global reservation
// per (wg,bucket), then write packed records (src<<BK | dst&(BN-1)) densely.
__global__ __launch_bounds__(256) void pass2_kernel(
    const int* __restrict__ ei, const int* __restrict__ bbase,
    int* __restrict__ gcur, unsigned* __restrict__ rec, int E, int NB)
{
    __shared__ int h[1024];
    __shared__ int gslot[1024];
    int t = threadIdx.x;
    for (int i = t; i < NB; i += 256) h[i] = 0;
    __syncthreads();
    int base = blockIdx.x * 4096;
    unsigned rr[16]; int bb[16];
#pragma unroll
    for (int i = 0; i < 16; i++) {
        int e = base + i * 256 + t;
        if (e < E) {
            int s = ei[e];
            int d = ei[(size_t)E + e];
            bb[i] = d >> BK;
            rr[i] = ((unsigned)s << BK) | (unsigned)(d & (BN - 1));
            atomicAdd(&h[bb[i]], 1);
        } else bb[i] = -1;
    }
    __syncthreads();
    for (int i = t; i < NB; i += 256) {
        int c = h[i];
        if (c > 0) gslot[i] = bbase[i] + atomicAdd(&gcur[i], c);
        h[i] = 0;  // reuse as local cursor
    }
    __syncthreads();
#pragma unroll
    for (int i = 0; i < 16; i++) {
        if (bb[i] >= 0) {
            int r = atomicAdd(&h[bb[i]], 1);
            rec[gslot[bb[i]] + r] = rr[i];
        }
    }
}

// Per-bucket weighted degree + count via LDS accumulators.
// dinv = rsqrt(1 + sum_w); rcnt = 1/(1 + count).
__global__ __launch_bounds__(256) void deg_kernel(
    const unsigned* __restrict__ rec, const int* __restrict__ bbase,
    const float* __restrict__ pos,
    float* __restrict__ dinv, float* __restrict__ rcnt, int N)
{
    __shared__ float posL[BN * 3];
    __shared__ float ws[BN];
    __shared__ int cs[BN];
    int t = threadIdx.x;
    int nb0 = blockIdx.x << BK;
    for (int i = t; i < BN; i += 256) {
        int n = nb0 + i;
        float px = 0, py = 0, pz = 0;
        if (n < N) {
            px = pos[3 * (size_t)n + 0];
            py = pos[3 * (size_t)n + 1];
            pz = pos[3 * (size_t)n + 2];
        }
        posL[i * 3 + 0] = px; posL[i * 3 + 1] = py; posL[i * 3 + 2] = pz;
        ws[i] = 0.0f; cs[i] = 0;
    }
    __syncthreads();
    int rb = bbase[blockIdx.x], re = bbase[blockIdx.x + 1];
    for (int j = rb + t; j < re; j += 256) {
        unsigned r = rec[j];
        int s = r >> BK, dl = r & (BN - 1);
        float dx = posL[dl * 3 + 0] - pos[3 * (size_t)s + 0];
        float dy = posL[dl * 3 + 1] - pos[3 * (size_t)s + 1];
        float dz = posL[dl * 3 + 2] - pos[3 * (size_t)s + 2];
        float w = sqrtf(fmaf(dx, dx, fmaf(dy, dy, dz * dz)));
        atomicAdd(&ws[dl], w);
        atomicAdd(&cs[dl], 1);
    }
    __syncthreads();
    for (int i = t; i < BN; i += 256) {
        int n = nb0 + i;
        if (n < N) {
            dinv[n] = rsqrtf(1.0f + ws[i]);
            rcnt[n] = 1.0f / (float)(1 + cs[i]);
        }
    }
}

// x0 = sp(pos@Wi+bi); xwA = dinv[n] * (x0 @ W_g1)   (pre-scaled by dinv[src])
__global__ __launch_bounds__(256) void node_init(
    const float* __restrict__ pos,
    const float* __restrict__ W_init, const float* __restrict__ b_init,
    const float* __restrict__ W_g1, const float* __restrict__ dinv,
    float* __restrict__ xw, int N)
{
    __shared__ float sWi[ND * EM];
    __shared__ float sbi[EM];
    __shared__ float sW1[EM * EM];
    int t = threadIdx.x;
    if (t < ND * EM) sWi[t] = W_init[t];
    if (t < EM)      sbi[t] = b_init[t];
    sW1[t] = W_g1[t];
    __syncthreads();

    int n = blockIdx.x * 256 + t;
    if (n >= N) return;

    float p0 = pos[3 * (size_t)n + 0];
    float p1 = pos[3 * (size_t)n + 1];
    float p2 = pos[3 * (size_t)n + 2];

    float x0[EM];
#pragma unroll
    for (int j = 0; j < EM; j++) {
        float h = fmaf(p0, sWi[0 * EM + j],
                  fmaf(p1, sWi[1 * EM + j],
                  fmaf(p2, sWi[2 * EM + j], sbi[j])));
        x0[j] = sp(h);
    }
    float di = dinv[n];
    float o[EM];
#pragma unroll
    for (int k = 0; k < EM; k++) {
        float a = 0.0f;
#pragma unroll
        for (int j = 0; j < EM; j++) a = fmaf(x0[j], sW1[j * EM + k], a);
        o[k] = a * di;
    }
    float4* xo = (float4*)(xw + (size_t)n * EM);
#pragma unroll
    for (int q = 0; q < 4; q++)
        xo[q] = make_float4(o[4*q+0], o[4*q+1], o[4*q+2], o[4*q+3]);
}

// Fused per-bucket conv. 16 lanes per record; LDS float-atomic accumulation.
// xin is pre-scaled by dinv[src], so msg = (w*dinv[d]) * xin[s][c].
// Epilogue: x = sp((acc + dinv[n]*xin[n][c]) * rcnt + bias).
// mode 1: xout = dinv[n] * (x @ W)   (feeds next conv layer)
// mode 2: fused heads: y = sp(x@Wp1+bp1); out = (y@Wp2+bp2)/sig
__global__ __launch_bounds__(256) void conv_kernel(
    const unsigned* __restrict__ rec, const int* __restrict__ bbase,
    const float* __restrict__ pos, const float* __restrict__ dinv,
    const float* __restrict__ rcnt, const float* __restrict__ xin,
    const float* __restrict__ bias, const float* __restrict__ W,
    const float* __restrict__ W_p1, const float* __restrict__ b_p1,
    const float* __restrict__ W_p2, const float* __restrict__ b_p2,
    const float* __restrict__ sig,
    float* __restrict__ xout, int N, int mode)
{
    __shared__ float acc[BN * ACCP];    // 34.8 KB
    __shared__ float posL[BN * 3];      // 6 KB
    __shared__ float dinvL[BN];         // 2 KB
    __shared__ float sW[EM * EM];
    __shared__ float sb[EM];
    __shared__ float sP1[EM * EM];
    __shared__ float sbp1[EM];
    __shared__ float sP2[EM * ND];
    __shared__ float sbp2[ND];

    int t = threadIdx.x;
    int nb0 = blockIdx.x << BK;
    if (mode == 1) {
        sW[t] = W[t];
    } else {
        sP1[t] = W_p1[t];
        if (t < EM)      sbp1[t] = b_p1[t];
        if (t < EM * ND) sP2[t] = W_p2[t];
        if (t < ND)      sbp2[t] = b_p2[t];
    }
    if (t < EM) sb[t] = bias[t];
    for (int i = t; i < BN; i += 256) {
        int n = nb0 + i;
        float px = 0, py = 0, pz = 0, di = 0;
        if (n < N) {
            px = pos[3 * (size_t)n + 0];
            py = pos[3 * (size_t)n + 1];
            pz = pos[3 * (size_t)n + 2];
            di = dinv[n];
        }
        posL[i * 3 + 0] = px; posL[i * 3 + 1] = py; posL[i * 3 + 2] = pz;
        dinvL[i] = di;
    }
    for (int i = t; i < BN * ACCP; i += 256) acc[i] = 0.0f;
    __syncthreads();

    int rb = bbase[blockIdx.x], re = bbase[blockIdx.x + 1];
    int sub = t >> 4, c = t & 15;
    for (int j = rb + sub; j < re; j += 16) {
        unsigned r = rec[j];
        int s = r >> BK, dl = r & (BN - 1);
        float dx = posL[dl * 3 + 0] - pos[3 * (size_t)s + 0];
        float dy = posL[dl * 3 + 1] - pos[3 * (size_t)s + 1];
        float dz = posL[dl * 3 + 2] - pos[3 * (size_t)s + 2];
        float w = sqrtf(fmaf(dx, dx, fmaf(dy, dy, dz * dz)));
        float coef = w * dinvL[dl];
        float v = coef * xin[(size_t)s * EM + c];
        atomicAdd(&acc[dl * ACCP + c], v);
    }
    __syncthreads();

    int g = t >> 4;
    for (int i = g; i < BN; i += 16) {
        int n = nb0 + i;
        float xv = 0.0f;
        float rc = 0.0f;
        if (n < N) rc = rcnt[n];
        if (n < N) {
            float self = dinvL[i] * xin[(size_t)n * EM + c];
            xv = sp(fmaf(acc[i * ACCP + c] + self, rc, sb[c]));
        }
        acc[i * ACCP + c] = xv;   // same-wave lanes write then read (lockstep)
        if (n < N) {
            if (mode == 1) {
                float o = 0.0f;
#pragma unroll
                for (int jj = 0; jj < EM; jj++)
                    o = fmaf(acc[i * ACCP + jj], sW[jj * EM + c], o);
                xout[(size_t)n * EM + c] = dinvL[i] * o;
            } else {
                float a = sbp1[c];
#pragma unroll
                for (int jj = 0; jj < EM; jj++)
                    a = fmaf(acc[i * ACCP + jj], sP1[jj * EM + c], a);
                float y = sp(a);
                acc[i * ACCP + c] = y;   // lockstep write-then-read again
                if (c < ND) {
                    float o = sbp2[c];
#pragma unroll
                    for (int jj = 0; jj < EM; jj++)
                        o = fmaf(acc[i * ACCP + jj], sP2[jj * ND + c], o);
                    xout[(size_t)n * ND + c] = o / sig[n];
                }
            }
        }
    }
}

extern "C" void kernel_launch(void* const* d_in, const int* in_sizes, int n_in,
                              void* d_out, int out_size, void* d_ws, size_t ws_size,
                              hipStream_t stream) {
    const float* pos    = (const float*)d_in[0];
    const float* sig    = (const float*)d_in[1];
    const int*   ei     = (const int*)d_in[2];
    const float* W_init = (const float*)d_in[4];
    const float* b_init = (const float*)d_in[5];
    const float* W_g1   = (const float*)d_in[6];
    const float* b_g1   = (const float*)d_in[7];
    const float* W_g2   = (const float*)d_in[8];
    const float* b_g2   = (const float*)d_in[9];
    const float* W_p1   = (const float*)d_in[10];
    const float* b_p1   = (const float*)d_in[11];
    const float* W_p2   = (const float*)d_in[12];
    const float* b_p2   = (const float*)d_in[13];
    float* out = (float*)d_out;

    int N = in_sizes[0] / ND;
    int E = in_sizes[2] / 2;
    int NB = (N + BN - 1) >> BK;          // 977 for N=500000
    size_t Ns = (size_t)N, Es = (size_t)E;

    // ws layout (4B units): rec[E] | bbase[NB+1] | gcur[NB] | dinv[N] | rcnt[N] | xwA[16N] | xwB[16N]
    unsigned* rec = (unsigned*)d_ws;
    int* bbase = (int*)(rec + Es);
    int* gcur  = bbase + (NB + 1);
    float* dinv = (float*)(gcur + NB);
    float* rcnt = dinv + Ns;
    float* xwA  = rcnt + Ns;
    float* xwB  = xwA + Ns * EM;

    int nbN = (N + 255) / 256;
    int nbE4 = (E + 4095) / 4096;

    zero_gcur<<<1, 1024, 0, stream>>>(gcur, NB);
    hist_kernel<<<nbE4, 256, 0, stream>>>(ei, gcur, E, NB);
    scan_kernel<<<1, 1024, 0, stream>>>(gcur, bbase, NB, E);
    pass2_kernel<<<nbE4, 256, 0, stream>>>(ei, bbase, gcur, rec, E, NB);
    deg_kernel<<<NB, 256, 0, stream>>>(rec, bbase, pos, dinv, rcnt, N);
    node_init<<<nbN, 256, 0, stream>>>(pos, W_init, b_init, W_g1, dinv, xwA, N);
    conv_kernel<<<NB, 256, 0, stream>>>(rec, bbase, pos, dinv, rcnt, xwA, b_g1, W_g2,
                                        W_p1, b_p1, W_p2, b_p2, sig, xwB, N, 1);
    conv_kernel<<<NB, 256, 0, stream>>>(rec, bbase, pos, dinv, rcnt, xwB, b_g2, W_g2,
                                        W_p1, b_p1, W_p2, b_p2, sig, out, N, 2);
}

// Round 4
// 1924.588 us; speedup vs baseline: 1.4375x; 1.4375x over previous
//
#include <hip/hip_runtime.h>
#include <hip/hip_bf16.h>
#include <math.h>

// NODE_DIM=3, EMBED=16
#define ND 3
#define EM 16
#define BK 8             // log2(nodes per bucket)
#define BN 256           // nodes per bucket
#define ACCP 17          // padded LDS accumulator stride
#define HNB 2048         // max buckets (N=500000 -> NB=1954)

__device__ __forceinline__ float sp(float x) {
    // jax.nn.softplus = max(x,0) + log1p(exp(-|x|))
    return fmaxf(x, 0.0f) + log1pf(expf(-fabsf(x)));
}

// ---- bucket pipeline -------------------------------------------------------

__global__ __launch_bounds__(1024) void zero_gcur(int* __restrict__ gcur, int NB) {
    int i = blockIdx.x * 1024 + threadIdx.x;
    if (i < NB) gcur[i] = 0;
}

// Histogram of dst-buckets. 4096 edges per WG.
__global__ __launch_bounds__(256) void hist_kernel(
    const int* __restrict__ ei, int* __restrict__ gcur, int E, int NB)
{
    __shared__ int h[HNB];
    int t = threadIdx.x;
    for (int i = t; i < NB; i += 256) h[i] = 0;
    __syncthreads();
    int base = blockIdx.x * 4096;
#pragma unroll
    for (int i = 0; i < 16; i++) {
        int e = base + i * 256 + t;
        if (e < E) atomicAdd(&h[ei[(size_t)E + e] >> BK], 1);
    }
    __syncthreads();
    for (int i = t; i < NB; i += 256) if (h[i]) atomicAdd(&gcur[i], h[i]);
}

// Exclusive scan of bucket counts -> bbase[NB+1]; reset gcur (NB <= 2048).
__global__ __launch_bounds__(1024) void scan_kernel(
    int* __restrict__ gcur, int* __restrict__ bbase, int NB, int E)
{
    __shared__ int sd[1024];
    int t = threadIdx.x;
    int i0 = 2 * t, i1 = 2 * t + 1;
    int v0 = (i0 < NB) ? gcur[i0] : 0;
    int v1 = (i1 < NB) ? gcur[i1] : 0;
    int pv = v0 + v1;
    sd[t] = pv;
    __syncthreads();
    for (int off = 1; off < 1024; off <<= 1) {
        int a = (t >= off) ? sd[t - off] : 0;
        __syncthreads();
        sd[t] += a;
        __syncthreads();
    }
    int base = sd[t] - pv;  // exclusive prefix of this pair
    if (i0 < NB) { bbase[i0] = base;      gcur[i0] = 0; }
    if (i1 < NB) { bbase[i1] = base + v0; gcur[i1] = 0; }
    if (t == 0) bbase[NB] = E;
}

// Multisplit: stage 4096 edges in regs, LDS histogram, one global reservation
// per (wg,bucket), write packed records (src<<BK | dst&(BN-1)) densely.
__global__ __launch_bounds__(256) void pass2_kernel(
    const int* __restrict__ ei, const int* __restrict__ bbase,
    int* __restrict__ gcur, unsigned* __restrict__ rec, int E, int NB)
{
    __shared__ int h[HNB];
    __shared__ int gslot[HNB];
    int t = threadIdx.x;
    for (int i = t; i < NB; i += 256) h[i] = 0;
    __syncthreads();
    int base = blockIdx.x * 4096;
    unsigned rr[16]; int bb[16];
#pragma unroll
    for (int i = 0; i < 16; i++) {
        int e = base + i * 256 + t;
        if (e < E) {
            int s = ei[e];
            int d = ei[(size_t)E + e];
            bb[i] = d >> BK;
            rr[i] = ((unsigned)s << BK) | (unsigned)(d & (BN - 1));
            atomicAdd(&h[bb[i]], 1);
        } else bb[i] = -1;
    }
    __syncthreads();
    for (int i = t; i < NB; i += 256) {
        int c = h[i];
        if (c > 0) gslot[i] = bbase[i] + atomicAdd(&gcur[i], c);
        h[i] = 0;  // reuse as local cursor
    }
    __syncthreads();
#pragma unroll
    for (int i = 0; i < 16; i++) {
        if (bb[i] >= 0) {
            int r = atomicAdd(&h[bb[i]], 1);
            rec[gslot[bb[i]] + r] = rr[i];
        }
    }
}

// Per-bucket weighted degree + count; dinv = rsqrt(1+sum_w); rcnt = 1/(1+cnt).
__global__ __launch_bounds__(256) void deg_kernel(
    const unsigned* __restrict__ rec, const int* __restrict__ bbase,
    const float* __restrict__ pos,
    float* __restrict__ dinv, float* __restrict__ rcnt, int N)
{
    __shared__ float posL[BN * 3];
    __shared__ float ws[BN];
    __shared__ int cs[BN];
    int t = threadIdx.x;
    int nb0 = blockIdx.x << BK;
    for (int i = t; i < BN; i += 256) {
        int n = nb0 + i;
        float px = 0, py = 0, pz = 0;
        if (n < N) {
            px = pos[3 * (size_t)n + 0];
            py = pos[3 * (size_t)n + 1];
            pz = pos[3 * (size_t)n + 2];
        }
        posL[i * 3 + 0] = px; posL[i * 3 + 1] = py; posL[i * 3 + 2] = pz;
        ws[i] = 0.0f; cs[i] = 0;
    }
    __syncthreads();
    int rb = bbase[blockIdx.x], re = bbase[blockIdx.x + 1];
    for (int j = rb + t; j < re; j += 256) {
        unsigned r = rec[j];
        int s = r >> BK, dl = r & (BN - 1);
        float dx = posL[dl * 3 + 0] - pos[3 * (size_t)s + 0];
        float dy = posL[dl * 3 + 1] - pos[3 * (size_t)s + 1];
        float dz = posL[dl * 3 + 2] - pos[3 * (size_t)s + 2];
        float w = sqrtf(fmaf(dx, dx, fmaf(dy, dy, dz * dz)));
        atomicAdd(&ws[dl], w);
        atomicAdd(&cs[dl], 1);
    }
    __syncthreads();
    for (int i = t; i < BN; i += 256) {
        int n = nb0 + i;
        if (n < N) {
            dinv[n] = rsqrtf(1.0f + ws[i]);
            rcnt[n] = 1.0f / (float)(1 + cs[i]);
        }
    }
}

// x0 = sp(pos@Wi+bi); xwA = dinv[n] * (x0 @ W_g1)   (pre-scaled by dinv[src])
__global__ __launch_bounds__(256) void node_init(
    const float* __restrict__ pos,
    const float* __restrict__ W_init, const float* __restrict__ b_init,
    const float* __restrict__ W_g1, const float* __restrict__ dinv,
    float* __restrict__ xw, int N)
{
    __shared__ float sWi[ND * EM];
    __shared__ float sbi[EM];
    __shared__ float sW1[EM * EM];
    int t = threadIdx.x;
    if (t < ND * EM) sWi[t] = W_init[t];
    if (t < EM)      sbi[t] = b_init[t];
    sW1[t] = W_g1[t];
    __syncthreads();

    int n = blockIdx.x * 256 + t;
    if (n >= N) return;

    float p0 = pos[3 * (size_t)n + 0];
    float p1 = pos[3 * (size_t)n + 1];
    float p2 = pos[3 * (size_t)n + 2];

    float x0[EM];
#pragma unroll
    for (int j = 0; j < EM; j++) {
        float h = fmaf(p0, sWi[0 * EM + j],
                  fmaf(p1, sWi[1 * EM + j],
                  fmaf(p2, sWi[2 * EM + j], sbi[j])));
        x0[j] = sp(h);
    }
    float di = dinv[n];
    float o[EM];
#pragma unroll
    for (int k = 0; k < EM; k++) {
        float a = 0.0f;
#pragma unroll
        for (int j = 0; j < EM; j++) a = fmaf(x0[j], sW1[j * EM + k], a);
        o[k] = a * di;
    }
    float4* xo = (float4*)(xw + (size_t)n * EM);
#pragma unroll
    for (int q = 0; q < 4; q++)
        xo[q] = make_float4(o[4*q+0], o[4*q+1], o[4*q+2], o[4*q+3]);
}

// Fused per-bucket conv. 16 lanes per record; LDS float-atomic accumulation.
// xin pre-scaled by dinv[src]; msg = (w*dinv[d]) * xin[s][c].
// mode 1: xout = dinv[n] * (sp(mean + bias) @ W)
// mode 2: y = sp(x@Wp1+bp1); out = (y@Wp2+bp2)/sig
__global__ __launch_bounds__(256, 6) void conv_kernel(
    const unsigned* __restrict__ rec, const int* __restrict__ bbase,
    const float* __restrict__ pos, const float* __restrict__ dinv,
    const float* __restrict__ rcnt, const float* __restrict__ xin,
    const float* __restrict__ bias, const float* __restrict__ W,
    const float* __restrict__ W_p1, const float* __restrict__ b_p1,
    const float* __restrict__ W_p2, const float* __restrict__ b_p2,
    const float* __restrict__ sig,
    float* __restrict__ xout, int N, int mode)
{
    __shared__ float acc[BN * ACCP];    // 17.4 KB
    __shared__ float4 posd[BN];         // 4 KB  (pos.xyz, dinv.w)
    __shared__ float sW[EM * EM];       // W (mode1) or W_p1 (mode2)
    __shared__ float sb[EM];
    __shared__ float sbp1[EM];
    __shared__ float sP2[EM * ND];
    __shared__ float sbp2[ND];

    int t = threadIdx.x;
    int nb0 = blockIdx.x << BK;
    if (mode == 1) {
        sW[t] = W[t];
    } else {
        sW[t] = W_p1[t];
        if (t < EM)      sbp1[t] = b_p1[t];
        if (t < EM * ND) sP2[t] = W_p2[t];
        if (t < ND)      sbp2[t] = b_p2[t];
    }
    if (t < EM) sb[t] = bias[t];
    for (int i = t; i < BN; i += 256) {
        int n = nb0 + i;
        float4 p = make_float4(0.f, 0.f, 0.f, 0.f);
        if (n < N) {
            p.x = pos[3 * (size_t)n + 0];
            p.y = pos[3 * (size_t)n + 1];
            p.z = pos[3 * (size_t)n + 2];
            p.w = dinv[n];
        }
        posd[i] = p;
    }
    for (int i = t; i < BN * ACCP; i += 256) acc[i] = 0.0f;
    __syncthreads();

    int rb = bbase[blockIdx.x], re = bbase[blockIdx.x + 1];
    int sub = t >> 4, c = t & 15;
    int j = rb + sub;
    // unrolled-by-4 main loop: 16 random xin lines in flight per wave
    for (; j + 48 < re; j += 64) {
        unsigned r0 = rec[j], r1 = rec[j + 16], r2 = rec[j + 32], r3 = rec[j + 48];
        int s0 = r0 >> BK, s1 = r1 >> BK, s2 = r2 >> BK, s3 = r3 >> BK;
        float x0 = xin[((size_t)s0 << 4) + c];
        float x1 = xin[((size_t)s1 << 4) + c];
        float x2 = xin[((size_t)s2 << 4) + c];
        float x3 = xin[((size_t)s3 << 4) + c];
        float a0x = pos[3*(size_t)s0], a0y = pos[3*(size_t)s0+1], a0z = pos[3*(size_t)s0+2];
        float a1x = pos[3*(size_t)s1], a1y = pos[3*(size_t)s1+1], a1z = pos[3*(size_t)s1+2];
        float a2x = pos[3*(size_t)s2], a2y = pos[3*(size_t)s2+1], a2z = pos[3*(size_t)s2+2];
        float a3x = pos[3*(size_t)s3], a3y = pos[3*(size_t)s3+1], a3z = pos[3*(size_t)s3+2];
        int d0 = r0 & (BN-1), d1 = r1 & (BN-1), d2 = r2 & (BN-1), d3 = r3 & (BN-1);
        float4 p0 = posd[d0], p1 = posd[d1], p2 = posd[d2], p3 = posd[d3];
        float dx, dy, dz, w;
        dx = p0.x - a0x; dy = p0.y - a0y; dz = p0.z - a0z;
        w = sqrtf(fmaf(dx, dx, fmaf(dy, dy, dz * dz)));
        atomicAdd(&acc[d0 * ACCP + c], w * p0.w * x0);
        dx = p1.x - a1x; dy = p1.y - a1y; dz = p1.z - a1z;
        w = sqrtf(fmaf(dx, dx, fmaf(dy, dy, dz * dz)));
        atomicAdd(&acc[d1 * ACCP + c], w * p1.w * x1);
        dx = p2.x - a2x; dy = p2.y - a2y; dz = p2.z - a2z;
        w = sqrtf(fmaf(dx, dx, fmaf(dy, dy, dz * dz)));
        atomicAdd(&acc[d2 * ACCP + c], w * p2.w * x2);
        dx = p3.x - a3x; dy = p3.y - a3y; dz = p3.z - a3z;
        w = sqrtf(fmaf(dx, dx, fmaf(dy, dy, dz * dz)));
        atomicAdd(&acc[d3 * ACCP + c], w * p3.w * x3);
    }
    for (; j < re; j += 16) {
        unsigned r = rec[j];
        int s = r >> BK, dl = r & (BN - 1);
        float xv = xin[((size_t)s << 4) + c];
        float4 p = posd[dl];
        float dx = p.x - pos[3*(size_t)s];
        float dy = p.y - pos[3*(size_t)s+1];
        float dz = p.z - pos[3*(size_t)s+2];
        float w = sqrtf(fmaf(dx, dx, fmaf(dy, dy, dz * dz)));
        atomicAdd(&acc[dl * ACCP + c], w * p.w * xv);
    }
    __syncthreads();

    int g = t >> 4;
    for (int i = g; i < BN; i += 16) {
        int n = nb0 + i;
        float xv = 0.0f;
        if (n < N) {
            float self = posd[i].w * xin[((size_t)n << 4) + c];
            xv = sp(fmaf(acc[i * ACCP + c] + self, rcnt[n], sb[c]));
        }
        acc[i * ACCP + c] = xv;   // same-wave 16-lane group: write then read (lockstep)
        if (n < N) {
            if (mode == 1) {
                float o = 0.0f;
#pragma unroll
                for (int jj = 0; jj < EM; jj++)
                    o = fmaf(acc[i * ACCP + jj], sW[jj * EM + c], o);
                xout[((size_t)n << 4) + c] = posd[i].w * o;
            } else {
                float a = sbp1[c];
#pragma unroll
                for (int jj = 0; jj < EM; jj++)
                    a = fmaf(acc[i * ACCP + jj], sW[jj * EM + c], a);
                float y = sp(a);
                acc[i * ACCP + c] = y;   // lockstep again
                if (c < ND) {
                    float o = sbp2[c];
#pragma unroll
                    for (int jj = 0; jj < EM; jj++)
                        o = fmaf(acc[i * ACCP + jj], sP2[jj * ND + c], o);
                    xout[(size_t)n * ND + c] = o / sig[n];
                }
            }
        }
    }
}

extern "C" void kernel_launch(void* const* d_in, const int* in_sizes, int n_in,
                              void* d_out, int out_size, void* d_ws, size_t ws_size,
                              hipStream_t stream) {
    const float* pos    = (const float*)d_in[0];
    const float* sig    = (const float*)d_in[1];
    const int*   ei     = (const int*)d_in[2];
    const float* W_init = (const float*)d_in[4];
    const float* b_init = (const float*)d_in[5];
    const float* W_g1   = (const float*)d_in[6];
    const float* b_g1   = (const float*)d_in[7];
    const float* W_g2   = (const float*)d_in[8];
    const float* b_g2   = (const float*)d_in[9];
    const float* W_p1   = (const float*)d_in[10];
    const float* b_p1   = (const float*)d_in[11];
    const float* W_p2   = (const float*)d_in[12];
    const float* b_p2   = (const float*)d_in[13];
    float* out = (float*)d_out;

    int N = in_sizes[0] / ND;
    int E = in_sizes[2] / 2;
    int NB = (N + BN - 1) >> BK;          // 1954 for N=500000
    size_t Ns = (size_t)N, Es = (size_t)E;

    // ws layout (4B units): rec[E] | bbase[NB+1] | gcur[NB] | dinv[N] | rcnt[N] | xwA[16N] | xwB[16N]
    unsigned* rec = (unsigned*)d_ws;
    int* bbase = (int*)(rec + Es);
    int* gcur  = bbase + (NB + 1);
    float* dinv = (float*)(gcur + NB);
    float* rcnt = dinv + Ns;
    float* xwA  = rcnt + Ns;
    float* xwB  = xwA + Ns * EM;

    int nbN = (N + 255) / 256;
    int nbE4 = (E + 4095) / 4096;

    zero_gcur<<<(NB + 1023) / 1024, 1024, 0, stream>>>(gcur, NB);
    hist_kernel<<<nbE4, 256, 0, stream>>>(ei, gcur, E, NB);
    scan_kernel<<<1, 1024, 0, stream>>>(gcur, bbase, NB, E);
    pass2_kernel<<<nbE4, 256, 0, stream>>>(ei, bbase, gcur, rec, E, NB);
    deg_kernel<<<NB, 256, 0, stream>>>(rec, bbase, pos, dinv, rcnt, N);
    node_init<<<nbN, 256, 0, stream>>>(pos, W_init, b_init, W_g1, dinv, xwA, N);
    conv_kernel<<<NB, 256, 0, stream>>>(rec, bbase, pos, dinv, rcnt, xwA, b_g1, W_g2,
                                        W_p1, b_p1, W_p2, b_p2, sig, xwB, N, 1);
    conv_kernel<<<NB, 256, 0, stream>>>(rec, bbase, pos, dinv, rcnt, xwB, b_g2, W_g2,
                                        W_p1, b_p1, W_p2, b_p2, sig, out, N, 2);
}